// Round 7
// baseline (505.934 us; speedup 1.0000x reference)
//
#include <hip/hip_runtime.h>
#include <hip/hip_cooperative_groups.h>

namespace cg = cooperative_groups;

typedef __attribute__((ext_vector_type(8))) short short8;
typedef __attribute__((ext_vector_type(4))) float f32x4;

// async global->LDS, 16B per lane, dest = wave-uniform base + lane*16
#define GLOAD16(g, l)                                                        \
  __builtin_amdgcn_global_load_lds(                                          \
      (const __attribute__((address_space(1))) unsigned int*)(g),            \
      (__attribute__((address_space(3))) unsigned int*)(l), 16, 0, 0)

__device__ __forceinline__ unsigned short f2bf(float f) {
  union { float f; unsigned int u; } v;
  v.f = f;
  unsigned int u = v.u;
  u += 0x7FFFu + ((u >> 16) & 1u);  // round-to-nearest-even
  return (unsigned short)(u >> 16);
}

__device__ __forceinline__ short8 pack8(float4 a, float4 b) {
  short8 r;
  r[0] = (short)f2bf(a.x); r[1] = (short)f2bf(a.y);
  r[2] = (short)f2bf(a.z); r[3] = (short)f2bf(a.w);
  r[4] = (short)f2bf(b.x); r[5] = (short)f2bf(b.y);
  r[6] = (short)f2bf(b.z); r[7] = (short)f2bf(b.w);
  return r;
}

#define BM 128
#define BN 128
#define BK 32

// ================== FUSED cooperative kernel (Dn=512 shape) =================
// grid=512 (2 blocks/CU guaranteed co-resident: 32KB LDS, <=256 VGPR), phases
// separated by grid.sync(). Phase bodies identical to the validated r5 kernels.
__global__ __launch_bounds__(256, 2)
void fused512_kernel(const float* __restrict__ emb, const int* __restrict__ labels,
                     const float* __restrict__ emb_mem, const int* __restrict__ lbl_mem,
                     unsigned short* __restrict__ refbf, float* __restrict__ sqb,
                     int* __restrict__ reflab, float* __restrict__ part,
                     float* __restrict__ rowloss, float* __restrict__ out,
                     int Bn, int Mn) {
  __shared__ __align__(16) char smem[32768];
  unsigned short* As = (unsigned short*)smem;
  unsigned short* Bs = (unsigned short*)(smem + 8192);
  f32x4* red4 = (f32x4*)smem;  // epilogue alias: [2][128][8] f32x4

  cg::grid_group grid = cg::this_grid();
  const int Dn = 512, ntiles = 256;
  int tid = threadIdx.x, lane = tid & 63, w = tid >> 6;
  int bid = blockIdx.x, G = gridDim.x;

  // ---------------- phase 1: fp32 -> bf16 + sq-norms + labels ----------------
  for (int row = bid * 4 + w; row < Mn; row += G * 4) {
    const float* src = (row < Bn) ? (emb + (size_t)row * Dn)
                                  : (emb_mem + (size_t)(row - Bn) * Dn);
    unsigned short* dst = refbf + (size_t)row * Dn;
    float s = 0.f;
    {
      int c0 = lane * 8;  // Dn=512: single pass
      float4 v0 = ((const float4*)(src + c0))[0];
      float4 v1 = ((const float4*)(src + c0))[1];
      s += v0.x * v0.x + v0.y * v0.y + v0.z * v0.z + v0.w * v0.w;
      s += v1.x * v1.x + v1.y * v1.y + v1.z * v1.z + v1.w * v1.w;
      *(short8*)(dst + c0) = pack8(v0, v1);
    }
#pragma unroll
    for (int off = 32; off; off >>= 1) s += __shfl_xor(s, off);
    if (lane == 0) {
      sqb[row] = s;
      reflab[row] = (row < Bn) ? labels[row] : lbl_mem[row - Bn];
    }
  }
  __threadfence();
  grid.sync();

  // ---------------- phase 2: GEMM + epilogue (r5-validated body) -------------
  int wr = w >> 1, wc = w & 1;
  int l16 = lane & 15, quad = lane >> 4;
  int lrow = lane >> 2, lk = lane & 3;
  int sr0 = w * 32 + lrow;
  int ca = (lk - (sr0 >> 1)) & 3;  // chunk rotation: conflict-free ds_read
  char* lA = (char*)As + w * 2048;
  char* lB = (char*)Bs + w * 2048;

  for (int t = bid; t < 2048; t += G) {
    int c = t & 7, g = t >> 3;        // XCD-sliced mapping (validated r3/r5)
    int jt = c * 32 + (g >> 3);
    int it = g & 7;
    int rowBase = it * BM, colBase = jt * BN;

    const char* gA0 = (const char*)refbf + (size_t)(rowBase + sr0) * 1024 + ca * 16;
    const char* gA1 = gA0 + 16 * 1024;
    const char* gB0 = (const char*)refbf + (size_t)(colBase + sr0) * 1024 + ca * 16;
    const char* gB1 = gB0 + 16 * 1024;

    f32x4 acc[4][4] = {};
#pragma unroll
    for (int kk = 0; kk < 16; ++kk) {
      GLOAD16(gA0 + kk * 64, lA);
      GLOAD16(gA1 + kk * 64, lA + 1024);
      GLOAD16(gB0 + kk * 64, lB);
      GLOAD16(gB1 + kk * 64, lB + 1024);
      __syncthreads();
      short8 af[4], bfr[4];
#pragma unroll
      for (int mi = 0; mi < 4; ++mi) {
        int row = wr * 64 + mi * 16 + l16;
        af[mi] = *(const short8*)&As[row * BK + ((quad + (row >> 1)) & 3) * 8];
      }
#pragma unroll
      for (int ni = 0; ni < 4; ++ni) {
        int row = wc * 64 + ni * 16 + l16;
        bfr[ni] = *(const short8*)&Bs[row * BK + ((quad + (row >> 1)) & 3) * 8];
      }
#pragma unroll
      for (int mi = 0; mi < 4; ++mi)
#pragma unroll
        for (int ni = 0; ni < 4; ++ni)
          acc[mi][ni] = __builtin_amdgcn_mfma_f32_16x16x32_bf16(
              af[mi], bfr[ni], acc[mi][ni], 0, 0, 0);
      __syncthreads();
    }

    float sqc[4];
    int labc[4];
#pragma unroll
    for (int ni = 0; ni < 4; ++ni) {
      int gcol = colBase + wc * 64 + ni * 16 + l16;
      sqc[ni] = sqb[gcol];
      labc[ni] = reflab[gcol];
    }
#pragma unroll
    for (int mi = 0; mi < 4; ++mi) {
      int lr0 = wr * 64 + mi * 16 + quad * 4;
#pragma unroll
      for (int r = 0; r < 4; ++r) {
        int lrl = lr0 + r;
        int grow = rowBase + lrl;
        float sqr = sqb[grow];
        int labr = reflab[grow];
        float ps = 0.f, ns = 0.f, cpk = 0.f;  // cpk = pos_cnt + 512*neg_cnt
#pragma unroll
        for (int ni = 0; ni < 4; ++ni) {
          int gcol = colBase + wc * 64 + ni * 16 + l16;
          float dist = fmaxf(sqr + sqc[ni] - 2.0f * acc[mi][ni][r], 0.f);
          bool self = (gcol == grow);  // idx_ref[j]!=i reduces to j!=i
          bool same = (labc[ni] == labr);
          if (same && !self && dist > 0.f) { ps += dist; cpk += 1.f; }
          if (!same && !self && dist < 1.f) { ns += 1.f - dist; cpk += 512.f; }
        }
        ps += __shfl_xor(ps, 8);
        ns += __shfl_xor(ns, 8);
        cpk += __shfl_xor(cpk, 8);
        if (l16 < 8) {
          f32x4 v = {ps, ns, cpk, 0.f};
          red4[(wc * BM + lrl) * 8 + l16] = v;
        }
      }
    }
    __syncthreads();
    if (tid < BM) {
      f32x4 s = {0.f, 0.f, 0.f, 0.f};
#pragma unroll
      for (int c2 = 0; c2 < 2; ++c2)
#pragma unroll
        for (int k = 0; k < 8; ++k)  // (k+tid)&7: lanes sweep all 32 banks
          s += red4[(c2 * BM + tid) * 8 + ((k + tid) & 7)];
      float nc = floorf(s[2] * (1.0f / 512.0f));
      float pc = s[2] - 512.f * nc;
      f32x4 o = {s[0], pc, s[1], nc};
      ((f32x4*)part)[(size_t)(rowBase + tid) * ntiles + jt] = o;  // [row][jt]
    }
    __syncthreads();  // red4 alias dead before next tile's GLOAD
  }
  __threadfence();
  grid.sync();

  // ---------------- phase 3: per-row fold over j-tiles (coalesced) -----------
  const f32x4* part4 = (const f32x4*)part;
  for (int gr = bid; gr < Bn; gr += G) {
    f32x4 a = part4[(size_t)gr * ntiles + tid];  // ntiles==256: one per thread
#pragma unroll
    for (int off = 32; off; off >>= 1) {
      a[0] += __shfl_xor(a[0], off);
      a[1] += __shfl_xor(a[1], off);
      a[2] += __shfl_xor(a[2], off);
      a[3] += __shfl_xor(a[3], off);
    }
    if (lane == 0) red4[w] = a;
    __syncthreads();
    if (tid == 0) {
      f32x4 s = red4[0] + red4[1] + red4[2] + red4[3];
      rowloss[gr] = s[0] / (s[1] + 1e-6f) + s[2] / (s[3] + 1e-6f);
    }
    __syncthreads();
  }
  __threadfence();
  grid.sync();

  // ---------------- phase 4: final sum (block 0) -----------------------------
  if (bid == 0) {
    float v = 0.f;
    for (int i = tid; i < Bn; i += 256) v += rowloss[i];
#pragma unroll
    for (int off = 32; off; off >>= 1) v += __shfl_xor(v, off);
    float* rs = (float*)smem;
    if (lane == 0) rs[w] = v;
    __syncthreads();
    if (tid == 0) out[0] = (rs[0] + rs[1] + rs[2] + rs[3]) / (float)Bn;
  }
}

// ================== fallback path: validated r5 kernels =====================
__global__ __launch_bounds__(256)
void prep2_kernel(const float* __restrict__ emb, const int* __restrict__ labels,
                  const float* __restrict__ emb_mem, const int* __restrict__ lbl_mem,
                  unsigned short* __restrict__ refbf, float* __restrict__ sqb,
                  int* __restrict__ reflab, float* __restrict__ facc,
                  int* __restrict__ fcnt, int Bn, int Dn, int Mn) {
  if (blockIdx.x == 0 && threadIdx.x == 0) { *facc = 0.f; *fcnt = 0; }
  int wid = threadIdx.x >> 6, lane = threadIdx.x & 63;
  int row = blockIdx.x * 4 + wid;
  if (row >= Mn) return;
  const float* src = (row < Bn) ? (emb + (size_t)row * Dn)
                                : (emb_mem + (size_t)(row - Bn) * Dn);
  unsigned short* dst = refbf + (size_t)row * Dn;
  float s = 0.f;
  for (int c0 = lane * 8; c0 < Dn; c0 += 64 * 8) {
    float4 v0 = ((const float4*)(src + c0))[0];
    float4 v1 = ((const float4*)(src + c0))[1];
    s += v0.x * v0.x + v0.y * v0.y + v0.z * v0.z + v0.w * v0.w;
    s += v1.x * v1.x + v1.y * v1.y + v1.z * v1.z + v1.w * v1.w;
    *(short8*)(dst + c0) = pack8(v0, v1);
  }
#pragma unroll
  for (int off = 32; off; off >>= 1) s += __shfl_xor(s, off);
  if (lane == 0) {
    sqb[row] = s;
    reflab[row] = (row < Bn) ? labels[row] : lbl_mem[row - Bn];
  }
}

__global__ __launch_bounds__(256)
void gemm_generic_kernel(const unsigned short* __restrict__ refbf,
                         const float* __restrict__ sqb,
                         const int* __restrict__ reflab,
                         float* __restrict__ part,
                         int Dn, int mtiles, int ntiles) {
  __shared__ unsigned short As[BM * BK];
  __shared__ unsigned short Bs[BN * BK];
  __shared__ f32x4 redbuf4[2 * BM];

  int bid = blockIdx.x;
  int it = bid % mtiles, jt = bid / mtiles;
  int rowBase = it * BM, colBase = jt * BN;
  int tid = threadIdx.x, lane = tid & 63, w = tid >> 6;
  int wr = w >> 1, wc = w & 1;
  int l16 = lane & 15, quad = lane >> 4;
  int lrow = lane >> 2, lk = lane & 3;
  size_t rowB = (size_t)Dn * 2;
  int r0 = w * 32 + lrow;
  int ca = (lk - (r0 >> 1)) & 3;
  const char* gA0 = (const char*)refbf + (size_t)(rowBase + r0) * rowB + ca * 16;
  const char* gA1 = gA0 + 16 * rowB;
  const char* gB0 = (const char*)refbf + (size_t)(colBase + r0) * rowB + ca * 16;
  const char* gB1 = gB0 + 16 * rowB;
  char* lA = (char*)As + w * 2048;
  char* lB = (char*)Bs + w * 2048;

  f32x4 acc[4][4] = {};
  for (int k0 = 0; k0 < Dn; k0 += BK) {
    int koff = k0 * 2;
    GLOAD16(gA0 + koff, lA);
    GLOAD16(gA1 + koff, lA + 1024);
    GLOAD16(gB0 + koff, lB);
    GLOAD16(gB1 + koff, lB + 1024);
    __syncthreads();
    short8 af[4], bfr[4];
#pragma unroll
    for (int mi = 0; mi < 4; ++mi) {
      int row = wr * 64 + mi * 16 + l16;
      af[mi] = *(const short8*)&As[row * BK + ((quad + (row >> 1)) & 3) * 8];
    }
#pragma unroll
    for (int ni = 0; ni < 4; ++ni) {
      int row = wc * 64 + ni * 16 + l16;
      bfr[ni] = *(const short8*)&Bs[row * BK + ((quad + (row >> 1)) & 3) * 8];
    }
#pragma unroll
    for (int mi = 0; mi < 4; ++mi)
#pragma unroll
      for (int ni = 0; ni < 4; ++ni)
        acc[mi][ni] = __builtin_amdgcn_mfma_f32_16x16x32_bf16(
            af[mi], bfr[ni], acc[mi][ni], 0, 0, 0);
    __syncthreads();
  }

  float sqc[4];
  int labc[4];
#pragma unroll
  for (int ni = 0; ni < 4; ++ni) {
    int gcol = colBase + wc * 64 + ni * 16 + l16;
    sqc[ni] = sqb[gcol];
    labc[ni] = reflab[gcol];
  }
#pragma unroll
  for (int mi = 0; mi < 4; ++mi) {
    int lr0 = wr * 64 + mi * 16 + quad * 4;
#pragma unroll
    for (int r = 0; r < 4; ++r) {
      int lrl = lr0 + r;
      int grow = rowBase + lrl;
      float sqr = sqb[grow];
      int labr = reflab[grow];
      float ps = 0.f, pc = 0.f, ns = 0.f, nc = 0.f;
#pragma unroll
      for (int ni = 0; ni < 4; ++ni) {
        int gcol = colBase + wc * 64 + ni * 16 + l16;
        float dist = fmaxf(sqr + sqc[ni] - 2.0f * acc[mi][ni][r], 0.f);
        bool self = (gcol == grow);
        bool same = (labc[ni] == labr);
        if (same && !self && dist > 0.f) { ps += dist; pc += 1.f; }
        if (!same && !self && dist < 1.f) { ns += 1.f - dist; nc += 1.f; }
      }
#pragma unroll
      for (int off = 8; off; off >>= 1) {
        ps += __shfl_xor(ps, off);
        pc += __shfl_xor(pc, off);
        ns += __shfl_xor(ns, off);
        nc += __shfl_xor(nc, off);
      }
      if (l16 == 0) {
        f32x4 v = {ps, pc, ns, nc};
        redbuf4[wc * BM + lrl] = v;
      }
    }
  }
  __syncthreads();
  if (tid < BM) {
    f32x4 s = redbuf4[tid] + redbuf4[BM + tid];
    ((f32x4*)part)[(size_t)(rowBase + tid) * ntiles + jt] = s;
  }
}

__global__ __launch_bounds__(256)
void reduce_final_kernel(const float* __restrict__ part,
                         float* __restrict__ facc, int* __restrict__ fcnt,
                         float* __restrict__ out, int Bn, int ntiles) {
  __shared__ float rsum[4];
  int tid = threadIdx.x, w = tid >> 6, lane = tid & 63;
  int row = blockIdx.x * 4 + w;
  const f32x4* part4 = (const f32x4*)part;
  float rl = 0.f;
  if (row < Bn) {
    f32x4 a = {0.f, 0.f, 0.f, 0.f};
    for (int j = lane; j < ntiles; j += 64)
      a += part4[(size_t)row * ntiles + j];
#pragma unroll
    for (int off = 32; off; off >>= 1) {
      a[0] += __shfl_xor(a[0], off);
      a[1] += __shfl_xor(a[1], off);
      a[2] += __shfl_xor(a[2], off);
      a[3] += __shfl_xor(a[3], off);
    }
    rl = a[0] / (a[1] + 1e-6f) + a[2] / (a[3] + 1e-6f);
  }
  if (lane == 0) rsum[w] = rl;
  __syncthreads();
  if (tid == 0) {
    float bs = rsum[0] + rsum[1] + rsum[2] + rsum[3];
    atomicAdd(facc, bs);
    __threadfence();
    int old = atomicAdd(fcnt, 1);
    if (old == (int)gridDim.x - 1) {
      __threadfence();
      float tot = atomicAdd(facc, 0.f);
      out[0] = tot / (float)Bn;
    }
  }
}

// ---------- host ----------
extern "C" void kernel_launch(void* const* d_in, const int* in_sizes, int n_in,
                              void* d_out, int out_size, void* d_ws, size_t ws_size,
                              hipStream_t stream) {
  const float* emb     = (const float*)d_in[0];
  const int*   labels  = (const int*)d_in[1];
  const float* emb_mem = (const float*)d_in[2];
  const int*   lbl_mem = (const int*)d_in[3];
  // d_in[4] (add_to_mem) does not affect the returned loss.

  int Bn = in_sizes[1];
  int Dn = in_sizes[0] / Bn;
  int Rn = in_sizes[3];
  int Mn = Bn + Rn;
  int mtiles = Bn / BM, ntiles = Mn / BN;

  char* ws = (char*)d_ws;
  unsigned short* refbf = (unsigned short*)ws;                 // Mn*Dn bf16
  size_t off = (size_t)Mn * Dn * 2;
  float* sqb     = (float*)(ws + off);                         // Mn
  int*   reflab  = (int*)(ws + off + (size_t)Mn * 4);          // Mn
  float* part    = (float*)(ws + off + (size_t)Mn * 8);        // Bn*ntiles*4
  float* rowloss = part + (size_t)Bn * ntiles * 4;             // Bn
  float* facc    = rowloss + Bn;                               // 1
  int*   fcnt    = (int*)(facc + 1);                           // 1
  float* outp    = (float*)d_out;

  bool fast = (Dn == 512 && mtiles == 8 && ntiles == 256);
  hipError_t cerr = hipErrorUnknown;
  if (fast) {
    void* args[] = {&emb, &labels, &emb_mem, &lbl_mem, &refbf, &sqb, &reflab,
                    &part, &rowloss, &outp, &Bn, &Mn};
    cerr = hipLaunchCooperativeKernel((void*)fused512_kernel, dim3(512),
                                      dim3(256), args, 0, stream);
  }
  if (cerr != hipSuccess) {
    // fallback: validated r5 3-dispatch path (also handles generic shapes)
    prep2_kernel<<<(Mn + 3) / 4, 256, 0, stream>>>(
        emb, labels, emb_mem, lbl_mem, refbf, sqb, reflab, facc, fcnt, Bn, Dn, Mn);
    gemm_generic_kernel<<<mtiles * ntiles, 256, 0, stream>>>(
        refbf, sqb, reflab, part, Dn, mtiles, ntiles);
    reduce_final_kernel<<<(Bn + 3) / 4, 256, 0, stream>>>(
        part, facc, fcnt, (float*)d_out, Bn, ntiles);
  }
}

// Round 8
// 162.861 us; speedup vs baseline: 3.1065x; 3.1065x over previous
//
#include <hip/hip_runtime.h>

typedef __attribute__((ext_vector_type(8))) short short8;
typedef __attribute__((ext_vector_type(4))) float f32x4;

// async global->LDS, 16B per lane, dest = wave-uniform base + lane*16
#define GLOAD16(g, l)                                                        \
  __builtin_amdgcn_global_load_lds(                                          \
      (const __attribute__((address_space(1))) unsigned int*)(g),            \
      (__attribute__((address_space(3))) unsigned int*)(l), 16, 0, 0)

__device__ __forceinline__ unsigned short f2bf(float f) {
  union { float f; unsigned int u; } v;
  v.f = f;
  unsigned int u = v.u;
  u += 0x7FFFu + ((u >> 16) & 1u);  // round-to-nearest-even
  return (unsigned short)(u >> 16);
}

__device__ __forceinline__ short8 pack8(float4 a, float4 b) {
  short8 r;
  r[0] = (short)f2bf(a.x); r[1] = (short)f2bf(a.y);
  r[2] = (short)f2bf(a.z); r[3] = (short)f2bf(a.w);
  r[4] = (short)f2bf(b.x); r[5] = (short)f2bf(b.y);
  r[6] = (short)f2bf(b.z); r[7] = (short)f2bf(b.w);
  return r;
}

#define BM 128
#define BN 128
#define BK 32

// ---------- kernel 1: prep, 4 rows per wave (4x MLP on the latency chain) --
__global__ __launch_bounds__(256)
void prep3_kernel(const float* __restrict__ emb, const int* __restrict__ labels,
                  const float* __restrict__ emb_mem, const int* __restrict__ lbl_mem,
                  unsigned short* __restrict__ refbf, float* __restrict__ sqb,
                  int* __restrict__ reflab, float* __restrict__ facc,
                  int* __restrict__ fcnt, int Bn, int Dn, int Mn) {
  if (blockIdx.x == 0 && threadIdx.x == 0) { *facc = 0.f; *fcnt = 0; }
  int w = threadIdx.x >> 6, lane = threadIdx.x & 63;
  int base = (blockIdx.x * 4 + w) * 4;
  const float* src[4];
  bool ok[4];
#pragma unroll
  for (int i = 0; i < 4; ++i) {
    int row = base + i;
    ok[i] = row < Mn;
    src[i] = !ok[i] ? emb
             : (row < Bn) ? (emb + (size_t)row * Dn)
                          : (emb_mem + (size_t)(row - Bn) * Dn);
  }
  float s[4] = {0.f, 0.f, 0.f, 0.f};
  for (int c0 = lane * 8; c0 < Dn; c0 += 64 * 8) {
    float4 a0[4], a1[4];
#pragma unroll
    for (int i = 0; i < 4; ++i) {   // 8 independent loads in flight
      a0[i] = ((const float4*)(src[i] + c0))[0];
      a1[i] = ((const float4*)(src[i] + c0))[1];
    }
#pragma unroll
    for (int i = 0; i < 4; ++i) {
      s[i] += a0[i].x * a0[i].x + a0[i].y * a0[i].y + a0[i].z * a0[i].z +
              a0[i].w * a0[i].w + a1[i].x * a1[i].x + a1[i].y * a1[i].y +
              a1[i].z * a1[i].z + a1[i].w * a1[i].w;
      if (ok[i]) *(short8*)(refbf + (size_t)(base + i) * Dn + c0) = pack8(a0[i], a1[i]);
    }
  }
#pragma unroll
  for (int off = 32; off; off >>= 1) {  // 4 interleaved independent chains
#pragma unroll
    for (int i = 0; i < 4; ++i) s[i] += __shfl_xor(s[i], off);
  }
  if (lane == 0) {
#pragma unroll
    for (int i = 0; i < 4; ++i) {
      int row = base + i;
      if (ok[i]) {
        sqb[row] = s[i];
        reflab[row] = (row < Bn) ? labels[row] : lbl_mem[row - Bn];
      }
    }
  }
}

// ---------- kernel 2a: GEMM, BM=128 x BN=256 (2 j-tiles/block) -------------
// Same 2-barrier K-loop, but 32 MFMAs + 12 ds_reads per wave per barrier pair
// (vs 16+8): barrier/drain overhead amortized over 2x work.
__global__ __launch_bounds__(256, 2)
void gemm512x2_kernel(const unsigned short* __restrict__ refbf,
                      const float* __restrict__ sqb,
                      const int* __restrict__ reflab,
                      float* __restrict__ part) {
  // staging: As 8KB + Bs 16KB = 24KB; epilogue red aliases full 32KB
  __shared__ __align__(16) char smem[32768];
  unsigned short* As = (unsigned short*)smem;
  unsigned short* Bs = (unsigned short*)(smem + 8192);
  f32x4* red4 = (f32x4*)smem;  // [2][128][8] f32x4

  const int npart = 128;               // j-pairs
  int bid = blockIdx.x;                // 1024 blocks
  int c = bid & 7, g = bid >> 3;       // XCD-sliced (validated r3/r5)
  int jp = c * 16 + (g >> 3);          // j-pair index [0,128)
  int it = g & 7;
  int rowBase = it * BM, colBase = jp * 256;

  int tid = threadIdx.x, lane = tid & 63, w = tid >> 6;
  int wr = w >> 1, wc = w & 1;         // 2x2 waves; each 64 rows x 128 cols
  int l16 = lane & 15, quad = lane >> 4;
  int lrow = lane >> 2, lk = lane & 3;

  // A staging: wave stages rows w*32..+32 (2 GLOADs)
  int ra = w * 32 + lrow;
  int caa = (lk - (ra >> 1)) & 3;      // chunk rotation: conflict-free ds_read
  const char* gA0 = (const char*)refbf + (size_t)(rowBase + ra) * 1024 + caa * 16;
  const char* gA1 = gA0 + 16 * 1024;
  char* lA = (char*)As + w * 2048;
  // B staging: wave stages rows w*64..+64 (4 GLOADs)
  int rb = w * 64 + lrow;
  int cab = (lk - (rb >> 1)) & 3;
  const char* gB0 = (const char*)refbf + (size_t)(colBase + rb) * 1024 + cab * 16;
  const char* gB1 = gB0 + 16 * 1024;
  const char* gB2 = gB0 + 32 * 1024;
  const char* gB3 = gB0 + 48 * 1024;
  char* lB = (char*)Bs + w * 4096;

  f32x4 acc[4][8] = {};
  for (int kk = 0; kk < 16; ++kk) {
    int ko = kk * 64;
    GLOAD16(gA0 + ko, lA);
    GLOAD16(gA1 + ko, lA + 1024);
    GLOAD16(gB0 + ko, lB);
    GLOAD16(gB1 + ko, lB + 1024);
    GLOAD16(gB2 + ko, lB + 2048);
    GLOAD16(gB3 + ko, lB + 3072);
    __syncthreads();
    short8 af[4], bfr[8];
#pragma unroll
    for (int mi = 0; mi < 4; ++mi) {
      int row = wr * 64 + mi * 16 + l16;
      af[mi] = *(const short8*)&As[row * BK + ((quad + (row >> 1)) & 3) * 8];
    }
#pragma unroll
    for (int ni = 0; ni < 8; ++ni) {
      int row = wc * 128 + ni * 16 + l16;
      bfr[ni] = *(const short8*)&Bs[row * BK + ((quad + (row >> 1)) & 3) * 8];
    }
#pragma unroll
    for (int mi = 0; mi < 4; ++mi)
#pragma unroll
      for (int ni = 0; ni < 8; ++ni)
        acc[mi][ni] = __builtin_amdgcn_mfma_f32_16x16x32_bf16(
            af[mi], bfr[ni], acc[mi][ni], 0, 0, 0);
    __syncthreads();
  }

  // ---- epilogue: packed counters (pc<=256, nc<=256: cpk exact), 1 shfl ----
  float sqc[8];
  int labc[8];
#pragma unroll
  for (int ni = 0; ni < 8; ++ni) {
    int gcol = colBase + wc * 128 + ni * 16 + l16;
    sqc[ni] = sqb[gcol];
    labc[ni] = reflab[gcol];
  }
#pragma unroll
  for (int mi = 0; mi < 4; ++mi) {
    int lr0 = wr * 64 + mi * 16 + quad * 4;
#pragma unroll
    for (int r = 0; r < 4; ++r) {
      int lrl = lr0 + r;
      int grow = rowBase + lrl;
      float sqr = sqb[grow];
      int labr = reflab[grow];
      float ps = 0.f, ns = 0.f, cpk = 0.f;  // cpk = pos_cnt + 512*neg_cnt
#pragma unroll
      for (int ni = 0; ni < 8; ++ni) {
        int gcol = colBase + wc * 128 + ni * 16 + l16;
        float dist = fmaxf(sqr + sqc[ni] - 2.0f * acc[mi][ni][r], 0.f);
        bool self = (gcol == grow);  // idx_ref[j]!=i reduces to j!=i
        bool same = (labc[ni] == labr);
        if (same && !self && dist > 0.f) { ps += dist; cpk += 1.f; }
        if (!same && !self && dist < 1.f) { ns += 1.f - dist; cpk += 512.f; }
      }
      ps += __shfl_xor(ps, 8);
      ns += __shfl_xor(ns, 8);
      cpk += __shfl_xor(cpk, 8);
      if (l16 < 8) {
        f32x4 v = {ps, ns, cpk, 0.f};
        red4[(wc * BM + lrl) * 8 + l16] = v;
      }
    }
  }
  __syncthreads();
  if (tid < BM) {
    f32x4 s = {0.f, 0.f, 0.f, 0.f};
#pragma unroll
    for (int c2 = 0; c2 < 2; ++c2)
#pragma unroll
      for (int k = 0; k < 8; ++k)  // (k+tid)&7: lanes sweep all 32 banks
        s += red4[(c2 * BM + tid) * 8 + ((k + tid) & 7)];
    float nc = floorf(s[2] * (1.0f / 512.0f));
    float pc = s[2] - 512.f * nc;
    f32x4 o = {s[0], pc, s[1], nc};
    ((f32x4*)part)[(size_t)(rowBase + tid) * npart + jp] = o;  // [row][jp]
  }
}

// ---------- kernel 2b: generic GEMM (fallback for other shapes) ------------
__global__ __launch_bounds__(256)
void gemm_generic_kernel(const unsigned short* __restrict__ refbf,
                         const float* __restrict__ sqb,
                         const int* __restrict__ reflab,
                         float* __restrict__ part,
                         int Dn, int mtiles, int ntiles) {
  __shared__ unsigned short As[BM * BK];
  __shared__ unsigned short Bs[BN * BK];
  __shared__ f32x4 redbuf4[2 * BM];

  int bid = blockIdx.x;
  int it = bid % mtiles, jt = bid / mtiles;
  int rowBase = it * BM, colBase = jt * BN;
  int tid = threadIdx.x, lane = tid & 63, w = tid >> 6;
  int wr = w >> 1, wc = w & 1;
  int l16 = lane & 15, quad = lane >> 4;
  int lrow = lane >> 2, lk = lane & 3;
  size_t rowB = (size_t)Dn * 2;
  int r0 = w * 32 + lrow;
  int ca = (lk - (r0 >> 1)) & 3;
  const char* gA0 = (const char*)refbf + (size_t)(rowBase + r0) * rowB + ca * 16;
  const char* gA1 = gA0 + 16 * rowB;
  const char* gB0 = (const char*)refbf + (size_t)(colBase + r0) * rowB + ca * 16;
  const char* gB1 = gB0 + 16 * rowB;
  char* lA = (char*)As + w * 2048;
  char* lB = (char*)Bs + w * 2048;

  f32x4 acc[4][4] = {};
  for (int k0 = 0; k0 < Dn; k0 += BK) {
    int koff = k0 * 2;
    GLOAD16(gA0 + koff, lA);
    GLOAD16(gA1 + koff, lA + 1024);
    GLOAD16(gB0 + koff, lB);
    GLOAD16(gB1 + koff, lB + 1024);
    __syncthreads();
    short8 af[4], bfr[4];
#pragma unroll
    for (int mi = 0; mi < 4; ++mi) {
      int row = wr * 64 + mi * 16 + l16;
      af[mi] = *(const short8*)&As[row * BK + ((quad + (row >> 1)) & 3) * 8];
    }
#pragma unroll
    for (int ni = 0; ni < 4; ++ni) {
      int row = wc * 64 + ni * 16 + l16;
      bfr[ni] = *(const short8*)&Bs[row * BK + ((quad + (row >> 1)) & 3) * 8];
    }
#pragma unroll
    for (int mi = 0; mi < 4; ++mi)
#pragma unroll
      for (int ni = 0; ni < 4; ++ni)
        acc[mi][ni] = __builtin_amdgcn_mfma_f32_16x16x32_bf16(
            af[mi], bfr[ni], acc[mi][ni], 0, 0, 0);
    __syncthreads();
  }

  float sqc[4];
  int labc[4];
#pragma unroll
  for (int ni = 0; ni < 4; ++ni) {
    int gcol = colBase + wc * 64 + ni * 16 + l16;
    sqc[ni] = sqb[gcol];
    labc[ni] = reflab[gcol];
  }
#pragma unroll
  for (int mi = 0; mi < 4; ++mi) {
    int lr0 = wr * 64 + mi * 16 + quad * 4;
#pragma unroll
    for (int r = 0; r < 4; ++r) {
      int lrl = lr0 + r;
      int grow = rowBase + lrl;
      float sqr = sqb[grow];
      int labr = reflab[grow];
      float ps = 0.f, pc = 0.f, ns = 0.f, nc = 0.f;
#pragma unroll
      for (int ni = 0; ni < 4; ++ni) {
        int gcol = colBase + wc * 64 + ni * 16 + l16;
        float dist = fmaxf(sqr + sqc[ni] - 2.0f * acc[mi][ni][r], 0.f);
        bool self = (gcol == grow);
        bool same = (labc[ni] == labr);
        if (same && !self && dist > 0.f) { ps += dist; pc += 1.f; }
        if (!same && !self && dist < 1.f) { ns += 1.f - dist; nc += 1.f; }
      }
#pragma unroll
      for (int off = 8; off; off >>= 1) {
        ps += __shfl_xor(ps, off);
        pc += __shfl_xor(pc, off);
        ns += __shfl_xor(ns, off);
        nc += __shfl_xor(nc, off);
      }
      if (l16 == 0) {
        f32x4 v = {ps, pc, ns, nc};
        redbuf4[wc * BM + lrl] = v;
      }
    }
  }
  __syncthreads();
  if (tid < BM) {
    f32x4 s = redbuf4[tid] + redbuf4[BM + tid];
    ((f32x4*)part)[(size_t)(rowBase + tid) * ntiles + jt] = s;
  }
}

// ---------- kernel 3: per-row fold + global sum (atomic + ticket) ----------
__global__ __launch_bounds__(256)
void reduce_final_kernel(const float* __restrict__ part,
                         float* __restrict__ facc, int* __restrict__ fcnt,
                         float* __restrict__ out, int Bn, int npart) {
  __shared__ float rsum[4];
  int tid = threadIdx.x, w = tid >> 6, lane = tid & 63;
  int row = blockIdx.x * 4 + w;
  const f32x4* part4 = (const f32x4*)part;
  float rl = 0.f;
  if (row < Bn) {
    f32x4 a = {0.f, 0.f, 0.f, 0.f};
    for (int j = lane; j < npart; j += 64)
      a += part4[(size_t)row * npart + j];
#pragma unroll
    for (int off = 32; off; off >>= 1) {
      a[0] += __shfl_xor(a[0], off);
      a[1] += __shfl_xor(a[1], off);
      a[2] += __shfl_xor(a[2], off);
      a[3] += __shfl_xor(a[3], off);
    }
    rl = a[0] / (a[1] + 1e-6f) + a[2] / (a[3] + 1e-6f);
  }
  if (lane == 0) rsum[w] = rl;
  __syncthreads();
  if (tid == 0) {
    float bs = rsum[0] + rsum[1] + rsum[2] + rsum[3];
    atomicAdd(facc, bs);
    __threadfence();
    int old = atomicAdd(fcnt, 1);
    if (old == (int)gridDim.x - 1) {
      __threadfence();
      float tot = atomicAdd(facc, 0.f);
      out[0] = tot / (float)Bn;
    }
  }
}

// ---------- host ----------
extern "C" void kernel_launch(void* const* d_in, const int* in_sizes, int n_in,
                              void* d_out, int out_size, void* d_ws, size_t ws_size,
                              hipStream_t stream) {
  const float* emb     = (const float*)d_in[0];
  const int*   labels  = (const int*)d_in[1];
  const float* emb_mem = (const float*)d_in[2];
  const int*   lbl_mem = (const int*)d_in[3];
  // d_in[4] (add_to_mem) does not affect the returned loss.

  int Bn = in_sizes[1];
  int Dn = in_sizes[0] / Bn;
  int Rn = in_sizes[3];
  int Mn = Bn + Rn;
  int mtiles = Bn / BM, ntiles = Mn / BN;

  char* ws = (char*)d_ws;
  unsigned short* refbf = (unsigned short*)ws;                 // Mn*Dn bf16
  size_t off = (size_t)Mn * Dn * 2;
  float* sqb    = (float*)(ws + off);                          // Mn
  int*   reflab = (int*)(ws + off + (size_t)Mn * 4);           // Mn
  float* part   = (float*)(ws + off + (size_t)Mn * 8);         // Bn*ntiles*4
  float* facc   = part + (size_t)Bn * ntiles * 4;              // 1
  int*   fcnt   = (int*)(facc + 1);                            // 1

  prep3_kernel<<<(Mn + 15) / 16, 256, 0, stream>>>(
      emb, labels, emb_mem, lbl_mem, refbf, sqb, reflab, facc, fcnt, Bn, Dn, Mn);

  bool fast = (Dn == 512 && mtiles == 8 && ntiles == 256);
  if (fast) {
    gemm512x2_kernel<<<1024, 256, 0, stream>>>(refbf, sqb, reflab, part);
    reduce_final_kernel<<<(Bn + 3) / 4, 256, 0, stream>>>(
        part, facc, fcnt, (float*)d_out, Bn, 128);
  } else {
    gemm_generic_kernel<<<mtiles * ntiles, 256, 0, stream>>>(
        refbf, sqb, reflab, part, Dn, mtiles, ntiles);
    reduce_final_kernel<<<(Bn + 3) / 4, 256, 0, stream>>>(
        part, facc, fcnt, (float*)d_out, Bn, ntiles);
  }
}

// Round 9
// 160.211 us; speedup vs baseline: 3.1579x; 1.0165x over previous
//
#include <hip/hip_runtime.h>

typedef __attribute__((ext_vector_type(8))) short short8;
typedef __attribute__((ext_vector_type(4))) float f32x4;

// async global->LDS, 16B per lane, dest = wave-uniform base + lane*16
#define GLOAD16(g, l)                                                        \
  __builtin_amdgcn_global_load_lds(                                          \
      (const __attribute__((address_space(1))) unsigned int*)(g),            \
      (__attribute__((address_space(3))) unsigned int*)(l), 16, 0, 0)

__device__ __forceinline__ unsigned short f2bf(float f) {
  union { float f; unsigned int u; } v;
  v.f = f;
  unsigned int u = v.u;
  u += 0x7FFFu + ((u >> 16) & 1u);  // round-to-nearest-even
  return (unsigned short)(u >> 16);
}

__device__ __forceinline__ short8 pack8(float4 a, float4 b) {
  short8 r;
  r[0] = (short)f2bf(a.x); r[1] = (short)f2bf(a.y);
  r[2] = (short)f2bf(a.z); r[3] = (short)f2bf(a.w);
  r[4] = (short)f2bf(b.x); r[5] = (short)f2bf(b.y);
  r[6] = (short)f2bf(b.z); r[7] = (short)f2bf(b.w);
  return r;
}

#define BM 128
#define BN 128
#define BK 32

// ---------- kernel 1: prep (r5-validated: 1 row/wave, 4 waves/block) -------
// NOTE r8 post-mortem: the 4-rows-per-wave variant (prep3) regressed ~25us;
// this exact body is the validated fast version. Do not "improve" blindly.
__global__ __launch_bounds__(256)
void prep2_kernel(const float* __restrict__ emb, const int* __restrict__ labels,
                  const float* __restrict__ emb_mem, const int* __restrict__ lbl_mem,
                  unsigned short* __restrict__ refbf, float* __restrict__ sqb,
                  int* __restrict__ reflab, float* __restrict__ facc,
                  int* __restrict__ fcnt, int Bn, int Dn, int Mn) {
  if (blockIdx.x == 0 && threadIdx.x == 0) { *facc = 0.f; *fcnt = 0; }
  int wid = threadIdx.x >> 6, lane = threadIdx.x & 63;
  int row = blockIdx.x * 4 + wid;
  if (row >= Mn) return;
  const float* src = (row < Bn) ? (emb + (size_t)row * Dn)
                                : (emb_mem + (size_t)(row - Bn) * Dn);
  unsigned short* dst = refbf + (size_t)row * Dn;
  float s = 0.f;
  for (int c0 = lane * 8; c0 < Dn; c0 += 64 * 8) {
    float4 v0 = ((const float4*)(src + c0))[0];
    float4 v1 = ((const float4*)(src + c0))[1];
    s += v0.x * v0.x + v0.y * v0.y + v0.z * v0.z + v0.w * v0.w;
    s += v1.x * v1.x + v1.y * v1.y + v1.z * v1.z + v1.w * v1.w;
    *(short8*)(dst + c0) = pack8(v0, v1);
  }
#pragma unroll
  for (int off = 32; off; off >>= 1) s += __shfl_xor(s, off);
  if (lane == 0) {
    sqb[row] = s;
    reflab[row] = (row < Bn) ? labels[row] : lbl_mem[row - Bn];
  }
}

// ---------- kernel 2a: GEMM, BM=128 x BN=256 (r8-validated, 53.5us) --------
__global__ __launch_bounds__(256, 2)
void gemm512x2_kernel(const unsigned short* __restrict__ refbf,
                      const float* __restrict__ sqb,
                      const int* __restrict__ reflab,
                      float* __restrict__ part) {
  // staging: As 8KB + Bs 16KB = 24KB; epilogue red aliases full 32KB
  __shared__ __align__(16) char smem[32768];
  unsigned short* As = (unsigned short*)smem;
  unsigned short* Bs = (unsigned short*)(smem + 8192);
  f32x4* red4 = (f32x4*)smem;  // [2][128][8] f32x4

  const int npart = 128;               // j-pairs
  int bid = blockIdx.x;                // 1024 blocks
  int c = bid & 7, g = bid >> 3;       // XCD-sliced (validated r3/r5)
  int jp = c * 16 + (g >> 3);          // j-pair index [0,128)
  int it = g & 7;
  int rowBase = it * BM, colBase = jp * 256;

  int tid = threadIdx.x, lane = tid & 63, w = tid >> 6;
  int wr = w >> 1, wc = w & 1;         // 2x2 waves; each 64 rows x 128 cols
  int l16 = lane & 15, quad = lane >> 4;
  int lrow = lane >> 2, lk = lane & 3;

  // A staging: wave stages rows w*32..+32 (2 GLOADs)
  int ra = w * 32 + lrow;
  int caa = (lk - (ra >> 1)) & 3;      // chunk rotation: conflict-free ds_read
  const char* gA0 = (const char*)refbf + (size_t)(rowBase + ra) * 1024 + caa * 16;
  const char* gA1 = gA0 + 16 * 1024;
  char* lA = (char*)As + w * 2048;
  // B staging: wave stages rows w*64..+64 (4 GLOADs)
  int rb = w * 64 + lrow;
  int cab = (lk - (rb >> 1)) & 3;
  const char* gB0 = (const char*)refbf + (size_t)(colBase + rb) * 1024 + cab * 16;
  const char* gB1 = gB0 + 16 * 1024;
  const char* gB2 = gB0 + 32 * 1024;
  const char* gB3 = gB0 + 48 * 1024;
  char* lB = (char*)Bs + w * 4096;

  f32x4 acc[4][8] = {};
  for (int kk = 0; kk < 16; ++kk) {
    int ko = kk * 64;
    GLOAD16(gA0 + ko, lA);
    GLOAD16(gA1 + ko, lA + 1024);
    GLOAD16(gB0 + ko, lB);
    GLOAD16(gB1 + ko, lB + 1024);
    GLOAD16(gB2 + ko, lB + 2048);
    GLOAD16(gB3 + ko, lB + 3072);
    __syncthreads();
    short8 af[4], bfr[8];
#pragma unroll
    for (int mi = 0; mi < 4; ++mi) {
      int row = wr * 64 + mi * 16 + l16;
      af[mi] = *(const short8*)&As[row * BK + ((quad + (row >> 1)) & 3) * 8];
    }
#pragma unroll
    for (int ni = 0; ni < 8; ++ni) {
      int row = wc * 128 + ni * 16 + l16;
      bfr[ni] = *(const short8*)&Bs[row * BK + ((quad + (row >> 1)) & 3) * 8];
    }
#pragma unroll
    for (int mi = 0; mi < 4; ++mi)
#pragma unroll
      for (int ni = 0; ni < 8; ++ni)
        acc[mi][ni] = __builtin_amdgcn_mfma_f32_16x16x32_bf16(
            af[mi], bfr[ni], acc[mi][ni], 0, 0, 0);
    __syncthreads();
  }

  // ---- epilogue: packed counters (cpk = pc + 512*nc, exact), 1 shfl ------
  float sqc[8];
  int labc[8];
#pragma unroll
  for (int ni = 0; ni < 8; ++ni) {
    int gcol = colBase + wc * 128 + ni * 16 + l16;
    sqc[ni] = sqb[gcol];
    labc[ni] = reflab[gcol];
  }
#pragma unroll
  for (int mi = 0; mi < 4; ++mi) {
    int lr0 = wr * 64 + mi * 16 + quad * 4;
#pragma unroll
    for (int r = 0; r < 4; ++r) {
      int lrl = lr0 + r;
      int grow = rowBase + lrl;
      float sqr = sqb[grow];
      int labr = reflab[grow];
      float ps = 0.f, ns = 0.f, cpk = 0.f;
#pragma unroll
      for (int ni = 0; ni < 8; ++ni) {
        int gcol = colBase + wc * 128 + ni * 16 + l16;
        float dist = fmaxf(sqr + sqc[ni] - 2.0f * acc[mi][ni][r], 0.f);
        bool self = (gcol == grow);  // idx_ref[j]!=i reduces to j!=i
        bool same = (labc[ni] == labr);
        if (same && !self && dist > 0.f) { ps += dist; cpk += 1.f; }
        if (!same && !self && dist < 1.f) { ns += 1.f - dist; cpk += 512.f; }
      }
      ps += __shfl_xor(ps, 8);
      ns += __shfl_xor(ns, 8);
      cpk += __shfl_xor(cpk, 8);
      if (l16 < 8) {
        f32x4 v = {ps, ns, cpk, 0.f};
        red4[(wc * BM + lrl) * 8 + l16] = v;
      }
    }
  }
  __syncthreads();
  if (tid < BM) {
    f32x4 s = {0.f, 0.f, 0.f, 0.f};
#pragma unroll
    for (int c2 = 0; c2 < 2; ++c2)
#pragma unroll
      for (int k = 0; k < 8; ++k)  // (k+tid)&7: lanes sweep all 32 banks
        s += red4[(c2 * BM + tid) * 8 + ((k + tid) & 7)];
    float nc = floorf(s[2] * (1.0f / 512.0f));
    float pc = s[2] - 512.f * nc;
    f32x4 o = {s[0], pc, s[1], nc};
    ((f32x4*)part)[(size_t)(rowBase + tid) * npart + jp] = o;  // [row][jp]
  }
}

// ---------- kernel 2b: generic GEMM (fallback for other shapes) ------------
__global__ __launch_bounds__(256)
void gemm_generic_kernel(const unsigned short* __restrict__ refbf,
                         const float* __restrict__ sqb,
                         const int* __restrict__ reflab,
                         float* __restrict__ part,
                         int Dn, int mtiles, int ntiles) {
  __shared__ unsigned short As[BM * BK];
  __shared__ unsigned short Bs[BN * BK];
  __shared__ f32x4 redbuf4[2 * BM];

  int bid = blockIdx.x;
  int it = bid % mtiles, jt = bid / mtiles;
  int rowBase = it * BM, colBase = jt * BN;
  int tid = threadIdx.x, lane = tid & 63, w = tid >> 6;
  int wr = w >> 1, wc = w & 1;
  int l16 = lane & 15, quad = lane >> 4;
  int lrow = lane >> 2, lk = lane & 3;
  size_t rowB = (size_t)Dn * 2;
  int r0 = w * 32 + lrow;
  int ca = (lk - (r0 >> 1)) & 3;
  const char* gA0 = (const char*)refbf + (size_t)(rowBase + r0) * rowB + ca * 16;
  const char* gA1 = gA0 + 16 * rowB;
  const char* gB0 = (const char*)refbf + (size_t)(colBase + r0) * rowB + ca * 16;
  const char* gB1 = gB0 + 16 * rowB;
  char* lA = (char*)As + w * 2048;
  char* lB = (char*)Bs + w * 2048;

  f32x4 acc[4][4] = {};
  for (int k0 = 0; k0 < Dn; k0 += BK) {
    int koff = k0 * 2;
    GLOAD16(gA0 + koff, lA);
    GLOAD16(gA1 + koff, lA + 1024);
    GLOAD16(gB0 + koff, lB);
    GLOAD16(gB1 + koff, lB + 1024);
    __syncthreads();
    short8 af[4], bfr[4];
#pragma unroll
    for (int mi = 0; mi < 4; ++mi) {
      int row = wr * 64 + mi * 16 + l16;
      af[mi] = *(const short8*)&As[row * BK + ((quad + (row >> 1)) & 3) * 8];
    }
#pragma unroll
    for (int ni = 0; ni < 4; ++ni) {
      int row = wc * 64 + ni * 16 + l16;
      bfr[ni] = *(const short8*)&Bs[row * BK + ((quad + (row >> 1)) & 3) * 8];
    }
#pragma unroll
    for (int mi = 0; mi < 4; ++mi)
#pragma unroll
      for (int ni = 0; ni < 4; ++ni)
        acc[mi][ni] = __builtin_amdgcn_mfma_f32_16x16x32_bf16(
            af[mi], bfr[ni], acc[mi][ni], 0, 0, 0);
    __syncthreads();
  }

  float sqc[4];
  int labc[4];
#pragma unroll
  for (int ni = 0; ni < 4; ++ni) {
    int gcol = colBase + wc * 64 + ni * 16 + l16;
    sqc[ni] = sqb[gcol];
    labc[ni] = reflab[gcol];
  }
#pragma unroll
  for (int mi = 0; mi < 4; ++mi) {
    int lr0 = wr * 64 + mi * 16 + quad * 4;
#pragma unroll
    for (int r = 0; r < 4; ++r) {
      int lrl = lr0 + r;
      int grow = rowBase + lrl;
      float sqr = sqb[grow];
      int labr = reflab[grow];
      float ps = 0.f, pc = 0.f, ns = 0.f, nc = 0.f;
#pragma unroll
      for (int ni = 0; ni < 4; ++ni) {
        int gcol = colBase + wc * 64 + ni * 16 + l16;
        float dist = fmaxf(sqr + sqc[ni] - 2.0f * acc[mi][ni][r], 0.f);
        bool self = (gcol == grow);
        bool same = (labc[ni] == labr);
        if (same && !self && dist > 0.f) { ps += dist; pc += 1.f; }
        if (!same && !self && dist < 1.f) { ns += 1.f - dist; nc += 1.f; }
      }
#pragma unroll
      for (int off = 8; off; off >>= 1) {
        ps += __shfl_xor(ps, off);
        pc += __shfl_xor(pc, off);
        ns += __shfl_xor(ns, off);
        nc += __shfl_xor(nc, off);
      }
      if (l16 == 0) {
        f32x4 v = {ps, pc, ns, nc};
        redbuf4[wc * BM + lrl] = v;
      }
    }
  }
  __syncthreads();
  if (tid < BM) {
    f32x4 s = redbuf4[tid] + redbuf4[BM + tid];
    ((f32x4*)part)[(size_t)(rowBase + tid) * ntiles + jt] = s;
  }
}

// ---------- kernel 3: per-row fold + global sum (atomic + ticket) ----------
__global__ __launch_bounds__(256)
void reduce_final_kernel(const float* __restrict__ part,
                         float* __restrict__ facc, int* __restrict__ fcnt,
                         float* __restrict__ out, int Bn, int npart) {
  __shared__ float rsum[4];
  int tid = threadIdx.x, w = tid >> 6, lane = tid & 63;
  int row = blockIdx.x * 4 + w;
  const f32x4* part4 = (const f32x4*)part;
  float rl = 0.f;
  if (row < Bn) {
    f32x4 a = {0.f, 0.f, 0.f, 0.f};
    for (int j = lane; j < npart; j += 64)
      a += part4[(size_t)row * npart + j];
#pragma unroll
    for (int off = 32; off; off >>= 1) {
      a[0] += __shfl_xor(a[0], off);
      a[1] += __shfl_xor(a[1], off);
      a[2] += __shfl_xor(a[2], off);
      a[3] += __shfl_xor(a[3], off);
    }
    rl = a[0] / (a[1] + 1e-6f) + a[2] / (a[3] + 1e-6f);
  }
  if (lane == 0) rsum[w] = rl;
  __syncthreads();
  if (tid == 0) {
    float bs = rsum[0] + rsum[1] + rsum[2] + rsum[3];
    atomicAdd(facc, bs);
    __threadfence();
    int old = atomicAdd(fcnt, 1);
    if (old == (int)gridDim.x - 1) {
      __threadfence();
      float tot = atomicAdd(facc, 0.f);
      out[0] = tot / (float)Bn;
    }
  }
}

// ---------- host ----------
extern "C" void kernel_launch(void* const* d_in, const int* in_sizes, int n_in,
                              void* d_out, int out_size, void* d_ws, size_t ws_size,
                              hipStream_t stream) {
  const float* emb     = (const float*)d_in[0];
  const int*   labels  = (const int*)d_in[1];
  const float* emb_mem = (const float*)d_in[2];
  const int*   lbl_mem = (const int*)d_in[3];
  // d_in[4] (add_to_mem) does not affect the returned loss.

  int Bn = in_sizes[1];
  int Dn = in_sizes[0] / Bn;
  int Rn = in_sizes[3];
  int Mn = Bn + Rn;
  int mtiles = Bn / BM, ntiles = Mn / BN;

  char* ws = (char*)d_ws;
  unsigned short* refbf = (unsigned short*)ws;                 // Mn*Dn bf16
  size_t off = (size_t)Mn * Dn * 2;
  float* sqb    = (float*)(ws + off);                          // Mn
  int*   reflab = (int*)(ws + off + (size_t)Mn * 4);           // Mn
  float* part   = (float*)(ws + off + (size_t)Mn * 8);         // Bn*ntiles*4
  float* facc   = part + (size_t)Bn * ntiles * 4;              // 1
  int*   fcnt   = (int*)(facc + 1);                            // 1

  prep2_kernel<<<(Mn + 3) / 4, 256, 0, stream>>>(
      emb, labels, emb_mem, lbl_mem, refbf, sqb, reflab, facc, fcnt, Bn, Dn, Mn);

  bool fast = (Dn == 512 && mtiles == 8 && ntiles == 256);
  if (fast) {
    gemm512x2_kernel<<<1024, 256, 0, stream>>>(refbf, sqb, reflab, part);
    reduce_final_kernel<<<(Bn + 3) / 4, 256, 0, stream>>>(
        part, facc, fcnt, (float*)d_out, Bn, 128);
  } else {
    gemm_generic_kernel<<<mtiles * ntiles, 256, 0, stream>>>(
        refbf, sqb, reflab, part, Dn, mtiles, ntiles);
    reduce_final_kernel<<<(Bn + 3) / 4, 256, 0, stream>>>(
        part, facc, fcnt, (float*)d_out, Bn, ntiles);
  }
}